// Round 1
// baseline (28.906 us; speedup 1.0000x reference)
//
#include <hip/hip_runtime.h>

#define NA 192
#define RCUT_R 5.0f
#define RCUT_A 3.5f
#define SR 32
#define SA 8
#define TT 8
#define NFEAT 96
#define NH 128
#define PI_F 3.14159265358979323846f

__device__ __forceinline__ float app_gauss(float x) {
    float a = 1.0f / (1.0f + x * (1.0f / 64.0f));
    float a2 = a * a, a4 = a2 * a2, a8 = a4 * a4, a16 = a8 * a8, a32 = a16 * a16;
    return a32 * a32;
}

__device__ __forceinline__ float fcut(float r, float rc) {
    return (r <= rc && r > 1e-8f) ? 0.5f * (1.0f + cosf(PI_F * r / rc)) : 0.0f;
}

__global__ __launch_bounds__(256) void feat_mlp_kernel(
    const float* __restrict__ pos, const float* __restrict__ spec,
    const float* __restrict__ Rs, const float* __restrict__ Rs_ang,
    const float* __restrict__ theta_s, const float* __restrict__ width,
    const float* __restrict__ width_ang, const float* __restrict__ zeta,
    const float* __restrict__ W1, const float* __restrict__ b1,
    const float* __restrict__ W2, const float* __restrict__ b2,
    const float* __restrict__ W3, const float* __restrict__ b3,
    float* __restrict__ e_atom)
{
    const int i = blockIdx.x;
    const int tid = threadIdx.x;
    const int lane = tid & 63;
    const int wid = tid >> 6;

    __shared__ float s_r[NA], s_sfc[NA];
    __shared__ float nb_x[NA], nb_y[NA], nb_z[NA], nb_r[NA], nb_w[NA];
    __shared__ float s_feat[NFEAT];
    __shared__ float s_red[8 * SR];
    __shared__ float s_ared[4][64];
    __shared__ int s_wcnt[4];
    __shared__ int s_nj;
    __shared__ float s_h1[NH], s_h2[NH];

    const float px = pos[3 * i + 0];
    const float py = pos[3 * i + 1];
    const float pz = pos[3 * i + 2];

    // ---- stage pairwise data + deterministic neighbor compaction ----
    float dx = 0.f, dy = 0.f, dz = 0.f, rr = 0.f, fw = 0.f;
    bool flag = false;
    {
        int j = tid;
        if (j < NA) {
            dx = px - pos[3 * j + 0];
            dy = py - pos[3 * j + 1];
            dz = pz - pos[3 * j + 2];
            rr = sqrtf(dx * dx + dy * dy + dz * dz + 1e-12f);
            s_r[j] = rr;
            float fcr = (j != i) ? fcut(rr, RCUT_R) : 0.0f;
            s_sfc[j] = fcr * spec[j];
            flag = (j != i) && (rr <= RCUT_A) && (rr > 1e-8f);
            fw = (flag ? fcut(rr, RCUT_A) : 0.0f) * spec[j];
        }
        unsigned long long mask = __ballot(flag);
        if (lane == 0) s_wcnt[wid] = __popcll(mask);
        __syncthreads();
        if (flag) {
            int off = 0;
            for (int w = 0; w < wid; ++w) off += s_wcnt[w];
            int p = off + __popcll(mask & ((1ull << lane) - 1ull));
            nb_x[p] = dx; nb_y[p] = dy; nb_z[p] = dz; nb_r[p] = rr; nb_w[p] = fw;
        }
        if (tid == 0) s_nj = s_wcnt[0] + s_wcnt[1] + s_wcnt[2] + s_wcnt[3];
        __syncthreads();
    }

    // ---- radial descriptors: G_rad[s] = sum_j appGauss(w*(r-Rs)^2)*fc*spec ----
    {
        const int s = tid & 31;
        const int g = tid >> 5;           // 8 groups
        const float Rsv = Rs[s];
        const float w0 = width[0];
        float acc = 0.0f;
        for (int j = g; j < NA; j += 8) {
            float sf = s_sfc[j];
            if (sf != 0.0f) {
                float d = s_r[j] - Rsv;
                acc += app_gauss(w0 * d * d) * sf;
            }
        }
        s_red[g * 32 + s] = acc;
    }
    __syncthreads();
    if (tid < 32) {
        float acc = 0.0f;
        for (int g = 0; g < 8; ++g) acc += s_red[g * 32 + tid];
        s_feat[tid] = acc;
    }

    // ---- angular descriptors ----
    const int nj = s_nj;
    float accA[64];
#pragma unroll
    for (int k = 0; k < 64; ++k) accA[k] = 0.0f;

    {
        const float wang = width_ang[0];
        const float zet = zeta[0];
        const float pref = exp2f(1.0f - zet);
        float cth[TT], sth[TT], RsA[SA];
#pragma unroll
        for (int t = 0; t < TT; ++t) { float th = theta_s[t]; cth[t] = cosf(th); sth[t] = sinf(th); }
#pragma unroll
        for (int s = 0; s < SA; ++s) RsA[s] = Rs_ang[s];

        const int npp = nj * nj;
        for (int p = tid; p < npp; p += 256) {
            int a = p / nj, b = p - a * nj;
            if (b <= a) continue;          // unordered pairs; 0.5 * ordered == unordered
            float ra = nb_r[a], rb = nb_r[b];
            float dot = nb_x[a] * nb_x[b] + nb_y[a] * nb_y[b] + nb_z[a] * nb_z[b];
            float ct = dot / (ra * rb + 1e-12f);
            ct = fminf(fmaxf(ct, -1.0f + 1e-6f), 1.0f - 1e-6f);
            float st = sqrtf(1.0f - ct * ct);
            float w2 = nb_w[a] * nb_w[b];
            if (w2 == 0.0f) continue;
            float rbar = 0.5f * (ra + rb);
            float radv[SA], angv[TT];
#pragma unroll
            for (int s = 0; s < SA; ++s) { float d = rbar - RsA[s]; radv[s] = app_gauss(wang * d * d); }
#pragma unroll
            for (int t = 0; t < TT; ++t) {
                float cdt = ct * cth[t] + st * sth[t];
                angv[t] = pref * powf(fmaxf(1.0f + cdt, 1e-7f), zet);
            }
#pragma unroll
            for (int s = 0; s < SA; ++s) {
                float ws = w2 * radv[s];
#pragma unroll
                for (int t = 0; t < TT; ++t) accA[s * TT + t] += ws * angv[t];
            }
        }
    }

    // reduce accA across 256 threads (wave butterfly, then 4-wave LDS sum)
#pragma unroll
    for (int k = 0; k < 64; ++k) {
        float v = accA[k];
        v += __shfl_xor(v, 1);  v += __shfl_xor(v, 2);  v += __shfl_xor(v, 4);
        v += __shfl_xor(v, 8);  v += __shfl_xor(v, 16); v += __shfl_xor(v, 32);
        accA[k] = v;
    }
    if (lane == 0) {
#pragma unroll
        for (int k = 0; k < 64; ++k) s_ared[wid][k] = accA[k];
    }
    __syncthreads();
    if (tid < 64) {
        s_feat[32 + tid] = s_ared[0][tid] + s_ared[1][tid] + s_ared[2][tid] + s_ared[3][tid];
    }
    __syncthreads();

    // ---- MLP: 96 -> 128 -> 128 -> 1 ----
    if (tid < NH) {
        float acc = b1[tid];
        for (int f = 0; f < NFEAT; ++f) acc += s_feat[f] * W1[f * NH + tid];
        s_h1[tid] = tanhf(acc);
    }
    __syncthreads();
    if (tid < NH) {
        float acc = b2[tid];
        for (int f = 0; f < NH; ++f) acc += s_h1[f] * W2[f * NH + tid];
        s_h2[tid] = tanhf(acc);
    }
    __syncthreads();
    if (tid < NH) {
        float v = s_h2[tid] * W3[tid];
        v += __shfl_xor(v, 1);  v += __shfl_xor(v, 2);  v += __shfl_xor(v, 4);
        v += __shfl_xor(v, 8);  v += __shfl_xor(v, 16); v += __shfl_xor(v, 32);
        if (lane == 0) s_ared[0][wid] = v;
    }
    __syncthreads();
    if (tid == 0) e_atom[i] = s_ared[0][0] + s_ared[0][1] + b3[0];
}

__global__ __launch_bounds__(64) void reduce_kernel(const float* __restrict__ e_atom,
                                                    float* __restrict__ out)
{
    int tid = threadIdx.x;
    float v = 0.0f;
    for (int k = tid; k < NA; k += 64) v += e_atom[k];
    v += __shfl_xor(v, 1);  v += __shfl_xor(v, 2);  v += __shfl_xor(v, 4);
    v += __shfl_xor(v, 8);  v += __shfl_xor(v, 16); v += __shfl_xor(v, 32);
    if (tid == 0) out[0] = v;
}

extern "C" void kernel_launch(void* const* d_in, const int* in_sizes, int n_in,
                              void* d_out, int out_size, void* d_ws, size_t ws_size,
                              hipStream_t stream)
{
    const float* pos       = (const float*)d_in[0];
    const float* spec      = (const float*)d_in[1];
    const float* Rs        = (const float*)d_in[2];
    const float* Rs_ang    = (const float*)d_in[3];
    const float* theta_s   = (const float*)d_in[4];
    const float* width     = (const float*)d_in[5];
    const float* width_ang = (const float*)d_in[6];
    const float* zeta      = (const float*)d_in[7];
    const float* W1        = (const float*)d_in[8];
    const float* b1        = (const float*)d_in[9];
    const float* W2        = (const float*)d_in[10];
    const float* b2        = (const float*)d_in[11];
    const float* W3        = (const float*)d_in[12];
    const float* b3        = (const float*)d_in[13];

    float* e_atom = (float*)d_ws;

    feat_mlp_kernel<<<NA, 256, 0, stream>>>(pos, spec, Rs, Rs_ang, theta_s, width,
                                            width_ang, zeta, W1, b1, W2, b2, W3, b3,
                                            e_atom);
    reduce_kernel<<<1, 64, 0, stream>>>(e_atom, (float*)d_out);
}